// Round 9
// baseline (390.421 us; speedup 1.0000x reference)
//
#include <hip/hip_runtime.h>
#include <stdint.h>

// SelfAttentionV3 with mask-compaction. B=8, S=2048, D=1024.
// Valid rows (mask==1) are compacted per batch (nv, idx); projections, scores,
// softmax, PV run on nv_pad rows/cols only. Masked q-rows get
// out = (mean Xv)·Wv + bv exactly (uniform softmax over all 2048 rows).
// GEMM core: bf16 MFMA 256x256 tile, BK=64, 16 micro-phase read-ahead schedule
// (frozen from R7), XOR-swizzled LDS, counted vmcnt, setprio, batch->XCD map.
//
// ws layout (bytes):
//   [0,    32M)  qc   bf16 [8][2048][1024]  (compacted Q proj)
//   [32M,  64M)  kc   bf16 [8][2048][1024]
//   [64M,  96M)  vcT  bf16 [8][1024][2048]  (compacted V proj, transposed)
//   [96M, 192M)  Xqc/Xkc/Xvc bf16 compacted inputs (dead after projAll)
//   [96M, 163M)  scores/P bf16 [8][2048][2048] (overlays Xc)
//   [192M,198M)  WqT/WkT/WvT bf16
//   [198M,199M)  idx[8][2048] int, nv[8], nvpad[8], partial f32, vmean f32

typedef unsigned short u16;
typedef __attribute__((ext_vector_type(8))) short short8;
typedef __attribute__((ext_vector_type(4))) float f32x4;

__device__ __forceinline__ u16 f2bf(float x) {
  unsigned u = __float_as_uint(x);
  return (u16)((u + 0x7FFFu + ((u >> 16) & 1u)) >> 16);  // RNE
}
__device__ __forceinline__ float bf2f(u16 h) {
  return __uint_as_float(((unsigned)h) << 16);
}

__device__ __forceinline__ void stage16(const void* g, void* l) {
  const __attribute__((address_space(1))) uint32_t* gp =
      (const __attribute__((address_space(1))) uint32_t*)(uintptr_t)g;
  __attribute__((address_space(3))) uint32_t* lp =
      (__attribute__((address_space(3))) uint32_t*)(uintptr_t)l;
  __builtin_amdgcn_global_load_lds(gp, lp, 16, 0, 0);
}

__device__ __forceinline__ short8 ld8(const char* p, int off) {
  return *(const short8*)(p + off);
}

// ---- mask prefix-scan: per batch -> idx list, nv, nvpad ----
__global__ __launch_bounds__(256) void maskscan(const int* __restrict__ mask,
                                                int* __restrict__ idxA,
                                                int* __restrict__ nvA,
                                                int* __restrict__ nvpadA) {
  const int b = blockIdx.x;
  const int t = threadIdx.x, lane = t & 63, w = t >> 6;
  const int* m = mask + b * 2048;
  int v[8], loc = 0;
#pragma unroll
  for (int i = 0; i < 8; ++i) { v[i] = m[t * 8 + i]; loc += v[i]; }
  int sc = loc;  // inclusive scan over 64 lanes
  for (int off = 1; off < 64; off <<= 1) {
    int n = __shfl_up(sc, off);
    if (lane >= off) sc += n;
  }
  __shared__ int wsum[4];
  if (lane == 63) wsum[w] = sc;
  __syncthreads();
  int woff = 0;
  for (int i = 0; i < w; ++i) woff += wsum[i];
  int pos = woff + sc - loc;  // exclusive prefix
#pragma unroll
  for (int i = 0; i < 8; ++i)
    if (v[i]) idxA[b * 2048 + (pos++)] = t * 8 + i;
  if (t == 255) {
    const int nv = woff + sc;
    nvA[b] = nv;
    nvpadA[b] = (nv + 255) & ~255;
  }
}

// ---- gather valid rows + fp32->bf16 ----
__global__ __launch_bounds__(256) void compactrow(const float* __restrict__ X,
                                                  const int* __restrict__ idxA,
                                                  const int* __restrict__ nvA,
                                                  u16* __restrict__ out) {
  const int b = blockIdx.y, j = blockIdx.x;
  if (j >= nvA[b]) return;
  const int src = idxA[b * 2048 + j];
  const float4* s = (const float4*)(X + ((size_t)b * 2048 + src) * 1024);
  ushort4* d = (ushort4*)(out + ((size_t)b * 2048 + j) * 1024);
  const float4 f = s[threadIdx.x];
  ushort4 o;
  o.x = f2bf(f.x); o.y = f2bf(f.y); o.z = f2bf(f.z); o.w = f2bf(f.w);
  d[threadIdx.x] = o;
}

// ---- column partial sums of Xv (all 2048 rows) ----
__global__ __launch_bounds__(256) void colpart(const float* __restrict__ X,
                                               float* __restrict__ partial) {
  const int b = blockIdx.x, dq = blockIdx.y, sck = blockIdx.z;
  const int d = dq * 256 + threadIdx.x;
  const float* p = X + ((size_t)b * 2048 + sck * 256) * 1024 + d;
  float s0 = 0, s1 = 0, s2 = 0, s3 = 0;
  for (int r = 0; r < 256; r += 4) {
    s0 += p[(size_t)(r + 0) * 1024];
    s1 += p[(size_t)(r + 1) * 1024];
    s2 += p[(size_t)(r + 2) * 1024];
    s3 += p[(size_t)(r + 3) * 1024];
  }
  partial[((size_t)b * 8 + sck) * 1024 + d] = (s0 + s1) + (s2 + s3);
}

// ---- vmean[b][c] = (meanXv[b]·Wv)[c] + bv[c]  (pure fp32) ----
__global__ __launch_bounds__(256) void vmeanproj(const float* __restrict__ partial,
                                                 const float* __restrict__ Wv,
                                                 const float* __restrict__ bv,
                                                 float* __restrict__ vmean) {
  const int b = blockIdx.x, cq = blockIdx.y;
  const int c = cq * 256 + threadIdx.x;
  float acc = bv[c];
  for (int d = 0; d < 1024; ++d) {
    float m = 0;
#pragma unroll
    for (int i = 0; i < 8; ++i) m += partial[((size_t)b * 8 + i) * 1024 + d];
    acc += m * (1.0f / 2048.0f) * Wv[(size_t)d * 1024 + c];
  }
  vmean[b * 1024 + c] = acc;
}

// ---- out rows for masked q: broadcast vmean ----
__global__ __launch_bounds__(256) void bcast(const int* __restrict__ mask,
                                             const float* __restrict__ vmean,
                                             float* __restrict__ out) {
  const int b = blockIdx.y, row = blockIdx.x;
  if (mask[b * 2048 + row] != 0) return;
  const float4 vv = ((const float4*)(vmean + b * 1024))[threadIdx.x];
  ((float4*)(out + ((size_t)b * 2048 + row) * 1024))[threadIdx.x] = vv;
}

__global__ __launch_bounds__(256) void wtrans(const float* __restrict__ W,
                                              u16* __restrict__ WT) {
  __shared__ float tile[32][33];
  const int tx = threadIdx.x, ty = threadIdx.y;  // 32 x 8
  const int d0 = blockIdx.y * 32, n0 = blockIdx.x * 32;
#pragma unroll
  for (int i = 0; i < 4; ++i)
    tile[ty + 8 * i][tx] = W[(size_t)(d0 + ty + 8 * i) * 1024 + n0 + tx];
  __syncthreads();
#pragma unroll
  for (int i = 0; i < 4; ++i)
    WT[(size_t)(n0 + ty + 8 * i) * 1024 + d0 + tx] = f2bf(tile[tx][ty + 8 * i]);
}

// ---- 16-micro-phase 256x256 GEMM core (frozen R7 schedule) ----
// MODE 0: combined projections (o=0 q, 1 k, 2 v-transposed), batched, early-exit
// MODE 2: scores = qc kc^T /32, bf16 out, exits on bm,bn >= nvpad
// MODE 3: PV, runtime K = nvpad[z], scatter epilogue via idx, rows < nv only

#define BAR __builtin_amdgcn_s_barrier()

#define RDQ(DST, K0, K1, QOFF)                              \
  {                                                         \
    DST[0][0] = ld8(K0, (QOFF));                            \
    DST[0][1] = ld8(K0, (QOFF) + 2048);                     \
    DST[1][0] = ld8(K1, (QOFF));                            \
    DST[1][1] = ld8(K1, (QOFF) + 2048);                     \
  }

#define RDB(DST, K0, K1, NH)                                \
  {                                                         \
    DST[0][0] = ld8(K0, (NH) * 4096);                       \
    DST[0][1] = ld8(K0, (NH) * 4096 + 2048);                \
    DST[1][0] = ld8(K1, (NH) * 4096);                       \
    DST[1][1] = ld8(K1, (NH) * 4096 + 2048);                \
  }

#define MQ(ACC, MB, NH, A2, B2)                                          \
  __builtin_amdgcn_s_setprio(1);                                         \
  {                                                                      \
    _Pragma("unroll") for (int ks_ = 0; ks_ < 2; ++ks_)                  \
        _Pragma("unroll") for (int m_ = 0; m_ < 2; ++m_)                 \
            _Pragma("unroll") for (int nf_ = 0; nf_ < 2; ++nf_)          \
                ACC[(MB) + m_][(NH) * 2 + nf_] =                         \
                    __builtin_amdgcn_mfma_f32_16x16x32_bf16(             \
                        A2[ks_][m_], B2[ks_][nf_],                       \
                        ACC[(MB) + m_][(NH) * 2 + nf_], 0, 0, 0);        \
  }                                                                      \
  __builtin_amdgcn_s_setprio(0);

template <int MODE>
__global__ __launch_bounds__(512, 2) void gemm8p(
    const u16* __restrict__ A, const u16* __restrict__ B,
    void* __restrict__ C, void* __restrict__ C1, void* __restrict__ C2,
    const float* __restrict__ b0, const float* __restrict__ b1,
    const float* __restrict__ b2,
    const int* __restrict__ nvpadA, const int* __restrict__ nvA,
    const int* __restrict__ idxA,
    int K, int lda, int ldb, int ldc,
    size_t Az, size_t Bz, size_t Cz) {
  __shared__ __attribute__((aligned(16))) char smem[131072];
  const int tid = threadIdx.x;
  const int lane = tid & 63;
  const int w = tid >> 6;
  const int wr = w >> 2;
  const int wc = w & 3;

  // decode: batch-per-XCD (z = bx & 7)
  const int bx = blockIdx.x;
  const int z = bx & 7;
  int r = bx >> 3;
  int bm, bn, o = 0;
  if constexpr (MODE == 0) { o = r >> 5; r &= 31; bm = r >> 2; bn = r & 3; }
  else if constexpr (MODE == 2) { bm = r >> 3; bn = r & 7; }
  else { bm = r >> 2; bn = r & 3; }

  const int nvp = nvpadA[z];
  if (bm * 256 >= nvp) return;
  if constexpr (MODE == 2) { if (bn * 256 >= nvp) return; }

  const u16* Ap = A;
  const u16* Bp = B;
  if constexpr (MODE == 0) {
    Ap += (size_t)o * (8u * 2048u * 1024u) + (size_t)z * (2048u * 1024u);
    Bp += (size_t)o * (1024u * 1024u);
  } else {
    Ap += (size_t)z * Az;
    Bp += (size_t)z * Bz;
  }
  const int Kz = (MODE == 3) ? nvp : K;
  const int half = Kz >> 7;  // iterations; 2 K-tiles (BK=64) each; Kz % 256 == 0

  // staging addressing: linear LDS dest, inverse-swizzled global source
  const int srow = w * 8 + (lane >> 3);
  const int scol = ((lane & 7) ^ (lane >> 3)) << 3;  // elems
  const u16* Ab0 = Ap + (size_t)(bm * 256 + srow) * lda + scol;
  const u16* Ab1 = Ab0 + (size_t)64 * lda;
  const u16* Ab2 = Ab0 + (size_t)128 * lda;
  const u16* Ab3 = Ab0 + (size_t)192 * lda;
  const u16* Bb0 = Bp + (size_t)(bn * 256 + srow) * ldb + scol;
  const u16* Bb1 = Bb0 + (size_t)64 * ldb;
  const u16* Bb2 = Bb0 + (size_t)128 * ldb;
  const u16* Bb3 = Bb0 + (size_t)192 * ldb;
  char* ldsW = smem + w * 1024;

  // fragment read bases
  const int fr = lane & 15;
  const int fq = lane >> 4;
  const int fx = (fr & 7) << 4;
  const char* pak0 = smem + wr * 16384 + fr * 128 + ((fq * 16) ^ fx);
  const char* pak1 = smem + wr * 16384 + fr * 128 + ((64 + fq * 16) ^ fx);
  const char* pak0b = pak0 + 65536;
  const char* pak1b = pak1 + 65536;
  const char* pbk0 = smem + 32768 + wc * 8192 + fr * 128 + ((fq * 16) ^ fx);
  const char* pbk1 = smem + 32768 + wc * 8192 + fr * 128 + ((64 + fq * 16) ^ fx);
  const char* pbk0b = pbk0 + 65536;
  const char* pbk1b = pbk1 + 65536;

  f32x4 acc0[4][4] = {};
  f32x4 acc1[4][4] = {};
  short8 aA[2][2], aB[2][2], bf0[2][2], bf1[2][2];

  // prologue
  stage16(Ab0, ldsW + 0);     stage16(Ab1, ldsW + 8192);
  stage16(Ab2, ldsW + 16384); stage16(Ab3, ldsW + 24576);
  stage16(Bb0, ldsW + 32768); stage16(Bb1, ldsW + 40960);
  stage16(Bb2, ldsW + 49152); stage16(Bb3, ldsW + 57344);
  stage16(Bb0 + 64, ldsW + 98304);  stage16(Bb1 + 64, ldsW + 106496);
  stage16(Bb2 + 64, ldsW + 114688); stage16(Bb3 + 64, ldsW + 122880);
  stage16(Ab0 + 64, ldsW + 65536);
  asm volatile("s_waitcnt vmcnt(5)" ::: "memory");
  BAR;
  RDQ(aA, pak0, pak1, 0);
  RDB(bf0, pbk0, pbk1, 0);

  int koff = 0;
  for (int i = 0; i < half; ++i) {
    const bool st = (i + 1 < half);
    const int o1 = koff + 64, o2 = koff + 128, o3 = koff + 192;

    // ---- half 0: tile t0 (buf0) ----
    RDB(bf1, pbk0, pbk1, 1);
    BAR;
    stage16(Ab1 + o1, ldsW + 65536 + 8192);
    MQ(acc0, 0, 0, aA, bf0);
    RDQ(aB, pak0, pak1, 4096);
    BAR;
    stage16(Ab2 + o1, ldsW + 65536 + 16384);
    MQ(acc0, 0, 1, aA, bf1);
    BAR;
    stage16(Ab3 + o1, ldsW + 65536 + 24576);
    MQ(acc0, 2, 0, aB, bf0);
    RDQ(aA, pak0, pak1, 8192);
    BAR;
    if (st) stage16(Bb0 + o2, ldsW + 32768);
    MQ(acc0, 2, 1, aB, bf1);
    BAR;
    if (st) stage16(Bb1 + o2, ldsW + 40960);
    MQ(acc1, 0, 0, aA, bf0);
    RDQ(aB, pak0, pak1, 12288);
    BAR;
    if (st) stage16(Bb2 + o2, ldsW + 49152);
    MQ(acc1, 0, 1, aA, bf1);
    BAR;
    if (st) stage16(Bb3 + o2, ldsW + 57344);
    MQ(acc1, 2, 0, aB, bf0);
    if (st) { asm volatile("s_waitcnt vmcnt(4)" ::: "memory"); }
    else    { asm volatile("s_waitcnt vmcnt(0)" ::: "memory"); }
    BAR;
    RDQ(aA, pak0b, pak1b, 0);
    RDB(bf0, pbk0b, pbk1b, 0);
    if (st) stage16(Ab0 + o2, ldsW + 0);
    MQ(acc1, 2, 1, aB, bf1);

    // ---- half 1: tile t1 (buf1) ----
    RDB(bf1, pbk0b, pbk1b, 1);
    BAR;
    if (st) stage16(Ab1 + o2, ldsW + 8192);
    MQ(acc0, 0, 0, aA, bf0);
    RDQ(aB, pak0b, pak1b, 4096);
    BAR;
    if (st) stage16(Ab2 + o2, ldsW + 16384);
    MQ(acc0, 0, 1, aA, bf1);
    BAR;
    if (st) stage16(Ab3 + o2, ldsW + 24576);
    MQ(acc0, 2, 0, aB, bf0);
    RDQ(aA, pak0b, pak1b, 8192);
    BAR;
    if (st) stage16(Bb0 + o3, ldsW + 98304);
    MQ(acc0, 2, 1, aB, bf1);
    BAR;
    if (st) stage16(Bb1 + o3, ldsW + 106496);
    MQ(acc1, 0, 0, aA, bf0);
    RDQ(aB, pak0b, pak1b, 12288);
    BAR;
    if (st) stage16(Bb2 + o3, ldsW + 114688);
    MQ(acc1, 0, 1, aA, bf1);
    BAR;
    if (st) stage16(Bb3 + o3, ldsW + 122880);
    MQ(acc1, 2, 0, aB, bf0);
    if (st) { asm volatile("s_waitcnt vmcnt(4)" ::: "memory"); }
    else    { asm volatile("s_waitcnt vmcnt(0)" ::: "memory"); }
    BAR;
    RDQ(aA, pak0, pak1, 0);
    RDB(bf0, pbk0, pbk1, 0);
    if (st) stage16(Ab0 + o3, ldsW + 65536);
    MQ(acc1, 2, 1, aB, bf1);

    koff += 128;
  }

  // epilogue. D frag layout: col = fr, row = fq*4 + j.
  const int colb = bn * 256 + wc * 64 + fr;
#pragma unroll
  for (int mh = 0; mh < 2; ++mh) {
    f32x4(&ac)[4][4] = mh ? acc1 : acc0;
    const int rowl = bm * 256 + wr * 128 + mh * 64 + fq * 4;  // local row
    if constexpr (MODE == 0) {
      if (o < 2) {
        const float* bp = o ? b1 : b0;
        u16* Cb = (u16*)(o ? C1 : C) + (size_t)z * (2048u * 1024u);
#pragma unroll
        for (int mf = 0; mf < 4; ++mf)
#pragma unroll
          for (int n = 0; n < 4; ++n) {
            const int c = colb + n * 16;
            const float bv = bp[c];
#pragma unroll
            for (int j = 0; j < 4; ++j)
              Cb[(size_t)(rowl + mf * 16 + j) * 1024 + c] =
                  f2bf(ac[mf][n][j] + bv);
          }
      } else {
        u16* Cb = (u16*)C2;  // vcT [8][1024][2048]
#pragma unroll
        for (int mf = 0; mf < 4; ++mf) {
          const int s_ = rowl + mf * 16;
#pragma unroll
          for (int n = 0; n < 4; ++n) {
            const int c = colb + n * 16;
            const float bv = b2[c];
            ushort4 ov;
            ov.x = f2bf(ac[mf][n][0] + bv);
            ov.y = f2bf(ac[mf][n][1] + bv);
            ov.z = f2bf(ac[mf][n][2] + bv);
            ov.w = f2bf(ac[mf][n][3] + bv);
            *(ushort4*)&Cb[((size_t)z * 1024 + c) * 2048 + s_] = ov;
          }
        }
      }
    } else if constexpr (MODE == 2) {
      u16* Cb = (u16*)C + (size_t)z * Cz;
#pragma unroll
      for (int mf = 0; mf < 4; ++mf)
#pragma unroll
        for (int n = 0; n < 4; ++n) {
          const int c = colb + n * 16;
#pragma unroll
          for (int j = 0; j < 4; ++j)
            Cb[(size_t)(rowl + mf * 16 + j) * ldc + c] =
                f2bf(ac[mf][n][j] * 0.03125f);
        }
    } else {  // MODE 3: scatter to d_out via idx, rows < nv only
      const int nv = nvA[z];
      const int* idxp = idxA + z * 2048;
      float* Ob = (float*)C;
#pragma unroll
      for (int mf = 0; mf < 4; ++mf)
#pragma unroll
        for (int j = 0; j < 4; ++j) {
          const int rowc = rowl + mf * 16 + j;
          if (rowc < nv) {
            const int gr = idxp[rowc];
            float* orow = Ob + ((size_t)z * 2048 + gr) * 1024;
#pragma unroll
            for (int n = 0; n < 4; ++n) orow[colb + n * 16] = ac[mf][n][j];
          }
        }
    }
  }
}

// ---- softmax on compacted rows: cols < nv softmaxed, [nv, nvpad) zeroed ----
__global__ __launch_bounds__(256) void softmaxc(u16* __restrict__ scores,
                                                const int* __restrict__ nvA,
                                                const int* __restrict__ nvpadA) {
  const int b = blockIdx.y, row = blockIdx.x;
  const int nv = nvA[b];
  if (row >= nv) return;
  const int nvp = nvpadA[b];
  const int t = threadIdx.x, lane = t & 63, w = t >> 6;
  u16* sc = scores + ((size_t)b * 2048 + row) * 2048;
  const int c0 = t * 8;
  float v[8];
  if (c0 < nvp) {
    const ushort4 h0 = *(const ushort4*)&sc[c0];
    const ushort4 h1 = *(const ushort4*)&sc[c0 + 4];
    v[0] = bf2f(h0.x); v[1] = bf2f(h0.y); v[2] = bf2f(h0.z); v[3] = bf2f(h0.w);
    v[4] = bf2f(h1.x); v[5] = bf2f(h1.y); v[6] = bf2f(h1.z); v[7] = bf2f(h1.w);
  } else {
#pragma unroll
    for (int i = 0; i < 8; ++i) v[i] = 0.f;
  }
  float lmax = -3.0e38f;
#pragma unroll
  for (int i = 0; i < 8; ++i)
    if (c0 + i < nv) lmax = fmaxf(lmax, v[i]);
#pragma unroll
  for (int off = 32; off >= 1; off >>= 1) lmax = fmaxf(lmax, __shfl_xor(lmax, off));
  __shared__ float red[8];
  if (lane == 0) red[w] = lmax;
  __syncthreads();
  const float bmax = fmaxf(fmaxf(red[0], red[1]), fmaxf(red[2], red[3]));
  float e[8];
  float lsum = 0.f;
#pragma unroll
  for (int i = 0; i < 8; ++i) {
    e[i] = (c0 + i < nv) ? __expf(v[i] - bmax) : 0.f;
    lsum += e[i];
  }
#pragma unroll
  for (int off = 32; off >= 1; off >>= 1) lsum += __shfl_xor(lsum, off);
  if (lane == 0) red[4 + w] = lsum;
  __syncthreads();
  const float inv = 1.0f / ((red[4] + red[5]) + (red[6] + red[7]));
  if (c0 < nvp) {
    ushort4 o0, o1;
    o0.x = f2bf(e[0] * inv); o0.y = f2bf(e[1] * inv);
    o0.z = f2bf(e[2] * inv); o0.w = f2bf(e[3] * inv);
    o1.x = f2bf(e[4] * inv); o1.y = f2bf(e[5] * inv);
    o1.z = f2bf(e[6] * inv); o1.w = f2bf(e[7] * inv);
    *(ushort4*)&sc[c0] = o0;
    *(ushort4*)&sc[c0 + 4] = o1;
  }
}

extern "C" void kernel_launch(void* const* d_in, const int* in_sizes, int n_in,
                              void* d_out, int out_size, void* d_ws, size_t ws_size,
                              hipStream_t stream) {
  const float* in_q = (const float*)d_in[0];
  const float* in_k = (const float*)d_in[1];
  const float* in_v = (const float*)d_in[2];
  const int* mask = (const int*)d_in[3];
  const float* Wq = (const float*)d_in[4];
  const float* bq = (const float*)d_in[5];
  const float* Wk = (const float*)d_in[6];
  const float* bk = (const float*)d_in[7];
  const float* Wv = (const float*)d_in[8];
  const float* bv = (const float*)d_in[9];

  char* ws = (char*)d_ws;
  const size_t SZ = (size_t)16384 * 1024 * 2;  // 32M bytes
  u16* qc = (u16*)(ws);
  u16* kc = (u16*)(ws + SZ);
  u16* vcT = (u16*)(ws + 2 * SZ);
  u16* Xc = (u16*)(ws + 3 * SZ);        // Xqc, Xkc, Xvc (32M each)
  u16* Xqc = Xc;
  u16* Xkc = Xc + (size_t)8 * 2048 * 1024;
  u16* Xvc = Xkc + (size_t)8 * 2048 * 1024;
  u16* scores = (u16*)(ws + 3 * SZ);    // overlays Xc after projections
  u16* WqT = (u16*)(ws + 6 * SZ);
  u16* WkT = WqT + 1024 * 1024;
  u16* WvT = WkT + 1024 * 1024;
  char* misc = ws + 6 * SZ + 6 * 1024 * 1024;
  int* idxA = (int*)misc;               // [8][2048]
  int* nvA = idxA + 8 * 2048;
  int* nvpadA = nvA + 8;
  float* partial = (float*)(misc + 128 * 1024);  // [8][8][1024]
  float* vmean = partial + 8 * 8 * 1024;         // [8][1024]

  // 1) mask scan -> idx, nv, nvpad
  maskscan<<<8, 256, 0, stream>>>(mask, idxA, nvA, nvpadA);

  // 2) compact-convert valid rows; column partials of Xv for vmean
  compactrow<<<dim3(2048, 8), 256, 0, stream>>>(in_q, idxA, nvA, Xqc);
  compactrow<<<dim3(2048, 8), 256, 0, stream>>>(in_k, idxA, nvA, Xkc);
  compactrow<<<dim3(2048, 8), 256, 0, stream>>>(in_v, idxA, nvA, Xvc);
  colpart<<<dim3(8, 4, 8), 256, 0, stream>>>(in_v, partial);
  vmeanproj<<<dim3(8, 4), 256, 0, stream>>>(partial, Wv, bv, vmean);

  // 3) weight transposes
  dim3 wtb(32, 8);
  wtrans<<<dim3(32, 32), wtb, 0, stream>>>(Wq, WqT);
  wtrans<<<dim3(32, 32), wtb, 0, stream>>>(Wk, WkT);
  wtrans<<<dim3(32, 32), wtb, 0, stream>>>(Wv, WvT);

  // 4) all three projections, one dispatch: grid 8z * (3o * 8bm * 4bn) = 768
  gemm8p<0><<<768, 512, 0, stream>>>(
      Xqc, WqT, qc, kc, vcT, bq, bk, bv, nvpadA, nvA, idxA,
      1024, 1024, 1024, 1024, 0, 0, 0);

  // 5) scores[b] = qc kc^T / 32 : grid 8z * (8bm * 8bn) = 512
  gemm8p<2><<<512, 512, 0, stream>>>(
      qc, kc, scores, nullptr, nullptr, nullptr, nullptr, nullptr,
      nvpadA, nvA, idxA, 1024, 1024, 1024, 2048,
      (size_t)2048 * 1024, (size_t)2048 * 1024, (size_t)2048 * 2048);

  // 6) compacted softmax (in place)
  softmaxc<<<dim3(2048, 8), 256, 0, stream>>>(scores, nvA, nvpadA);

  // 7) PV with scatter: grid 8z * (8bm * 4bn) = 256; K = nvpad[z]
  gemm8p<3><<<256, 512, 0, stream>>>(
      scores, vcT, d_out, nullptr, nullptr, nullptr, nullptr, nullptr,
      nvpadA, nvA, idxA, 0, 2048, 2048, 1024,
      (size_t)2048 * 2048, (size_t)1024 * 2048, 0);

  // 8) masked q-rows: out = vmean
  bcast<<<dim3(2048, 8), 256, 0, stream>>>(mask, vmean, (float*)d_out);
}

// Round 10
// 295.325 us; speedup vs baseline: 1.3220x; 1.3220x over previous
//
#include <hip/hip_runtime.h>
#include <stdint.h>

// SelfAttentionV3 with mask-compaction. B=8, S=2048, D=1024.
// Valid rows (mask==1) are compacted per batch (nv, idx); projections, scores,
// softmax, PV run on nv_pad rows/cols only. Masked q-rows get
// out = (mean Xv)·Wv + bv exactly (uniform softmax over all 2048 rows).
// GEMM core: bf16 MFMA 256x256 tile, BK=64, 16 micro-phase read-ahead schedule
// (frozen from R7), XOR-swizzled LDS, counted vmcnt, setprio, batch->XCD map.
// R10: vmeanproj (122us serial GEMV) -> meanx/vpartk/vmeanred parallel path.

typedef unsigned short u16;
typedef __attribute__((ext_vector_type(8))) short short8;
typedef __attribute__((ext_vector_type(4))) float f32x4;

__device__ __forceinline__ u16 f2bf(float x) {
  unsigned u = __float_as_uint(x);
  return (u16)((u + 0x7FFFu + ((u >> 16) & 1u)) >> 16);  // RNE
}
__device__ __forceinline__ float bf2f(u16 h) {
  return __uint_as_float(((unsigned)h) << 16);
}

__device__ __forceinline__ void stage16(const void* g, void* l) {
  const __attribute__((address_space(1))) uint32_t* gp =
      (const __attribute__((address_space(1))) uint32_t*)(uintptr_t)g;
  __attribute__((address_space(3))) uint32_t* lp =
      (__attribute__((address_space(3))) uint32_t*)(uintptr_t)l;
  __builtin_amdgcn_global_load_lds(gp, lp, 16, 0, 0);
}

__device__ __forceinline__ short8 ld8(const char* p, int off) {
  return *(const short8*)(p + off);
}

// ---- mask prefix-scan: per batch -> idx list, nv, nvpad ----
__global__ __launch_bounds__(256) void maskscan(const int* __restrict__ mask,
                                                int* __restrict__ idxA,
                                                int* __restrict__ nvA,
                                                int* __restrict__ nvpadA) {
  const int b = blockIdx.x;
  const int t = threadIdx.x, lane = t & 63, w = t >> 6;
  const int* m = mask + b * 2048;
  int v[8], loc = 0;
#pragma unroll
  for (int i = 0; i < 8; ++i) { v[i] = m[t * 8 + i]; loc += v[i]; }
  int sc = loc;  // inclusive scan over 64 lanes
  for (int off = 1; off < 64; off <<= 1) {
    int n = __shfl_up(sc, off);
    if (lane >= off) sc += n;
  }
  __shared__ int wsum[4];
  if (lane == 63) wsum[w] = sc;
  __syncthreads();
  int woff = 0;
  for (int i = 0; i < w; ++i) woff += wsum[i];
  int pos = woff + sc - loc;  // exclusive prefix
#pragma unroll
  for (int i = 0; i < 8; ++i)
    if (v[i]) idxA[b * 2048 + (pos++)] = t * 8 + i;
  if (t == 255) {
    const int nv = woff + sc;
    nvA[b] = nv;
    nvpadA[b] = (nv + 255) & ~255;
  }
}

// ---- gather valid rows + fp32->bf16 ----
__global__ __launch_bounds__(256) void compactrow(const float* __restrict__ X,
                                                  const int* __restrict__ idxA,
                                                  const int* __restrict__ nvA,
                                                  u16* __restrict__ out) {
  const int b = blockIdx.y, j = blockIdx.x;
  if (j >= nvA[b]) return;
  const int src = idxA[b * 2048 + j];
  const float4* s = (const float4*)(X + ((size_t)b * 2048 + src) * 1024);
  ushort4* d = (ushort4*)(out + ((size_t)b * 2048 + j) * 1024);
  const float4 f = s[threadIdx.x];
  ushort4 o;
  o.x = f2bf(f.x); o.y = f2bf(f.y); o.z = f2bf(f.z); o.w = f2bf(f.w);
  d[threadIdx.x] = o;
}

// ---- column partial sums of Xv (all 2048 rows) ----
__global__ __launch_bounds__(256) void colpart(const float* __restrict__ X,
                                               float* __restrict__ partial) {
  const int b = blockIdx.x, dq = blockIdx.y, sck = blockIdx.z;
  const int d = dq * 256 + threadIdx.x;
  const float* p = X + ((size_t)b * 2048 + sck * 256) * 1024 + d;
  float s0 = 0, s1 = 0, s2 = 0, s3 = 0;
  for (int r = 0; r < 256; r += 4) {
    s0 += p[(size_t)(r + 0) * 1024];
    s1 += p[(size_t)(r + 1) * 1024];
    s2 += p[(size_t)(r + 2) * 1024];
    s3 += p[(size_t)(r + 3) * 1024];
  }
  partial[((size_t)b * 8 + sck) * 1024 + d] = (s0 + s1) + (s2 + s3);
}

// ---- meanX[b][d] = (1/2048) * sum_i partial[b][i][d] ----
__global__ __launch_bounds__(256) void meanx(const float* __restrict__ partial,
                                             float* __restrict__ meanX) {
  const int b = blockIdx.x;
  const int d = blockIdx.y * 256 + threadIdx.x;
  float m = 0;
#pragma unroll
  for (int i = 0; i < 8; ++i) m += partial[((size_t)b * 8 + i) * 1024 + d];
  meanX[b * 1024 + d] = m * (1.0f / 2048.0f);
}

// ---- vpart[b][dk][c] = sum_{d in chunk dk} meanX[b][d] * Wv[d][c] ----
__global__ __launch_bounds__(256) void vpartk(const float* __restrict__ meanX,
                                              const float* __restrict__ Wv,
                                              float* __restrict__ vpart) {
  const int b = blockIdx.x, cq = blockIdx.y, dk = blockIdx.z;
  const int t = threadIdx.x;
  __shared__ float mx[128];
  if (t < 128) mx[t] = meanX[b * 1024 + dk * 128 + t];
  __syncthreads();
  const int c = cq * 256 + t;
  const float* wp = Wv + (size_t)(dk * 128) * 1024 + c;
  float acc = 0;
#pragma unroll 4
  for (int i = 0; i < 128; ++i) acc += mx[i] * wp[(size_t)i * 1024];
  vpart[((size_t)b * 8 + dk) * 1024 + c] = acc;
}

// ---- vmean[b][c] = bv[c] + sum_dk vpart[b][dk][c] ----
__global__ __launch_bounds__(256) void vmeanred(const float* __restrict__ vpart,
                                                const float* __restrict__ bv,
                                                float* __restrict__ vmean) {
  const int b = blockIdx.x;
  const int c = blockIdx.y * 256 + threadIdx.x;
  float acc = bv[c];
#pragma unroll
  for (int i = 0; i < 8; ++i) acc += vpart[((size_t)b * 8 + i) * 1024 + c];
  vmean[b * 1024 + c] = acc;
}

// ---- out rows for masked q: broadcast vmean ----
__global__ __launch_bounds__(256) void bcast(const int* __restrict__ mask,
                                             const float* __restrict__ vmean,
                                             float* __restrict__ out) {
  const int b = blockIdx.y, row = blockIdx.x;
  if (mask[b * 2048 + row] != 0) return;
  const float4 vv = ((const float4*)(vmean + b * 1024))[threadIdx.x];
  ((float4*)(out + ((size_t)b * 2048 + row) * 1024))[threadIdx.x] = vv;
}

__global__ __launch_bounds__(256) void wtrans(const float* __restrict__ W,
                                              u16* __restrict__ WT) {
  __shared__ float tile[32][33];
  const int tx = threadIdx.x, ty = threadIdx.y;  // 32 x 8
  const int d0 = blockIdx.y * 32, n0 = blockIdx.x * 32;
#pragma unroll
  for (int i = 0; i < 4; ++i)
    tile[ty + 8 * i][tx] = W[(size_t)(d0 + ty + 8 * i) * 1024 + n0 + tx];
  __syncthreads();
#pragma unroll
  for (int i = 0; i < 4; ++i)
    WT[(size_t)(n0 + ty + 8 * i) * 1024 + d0 + tx] = f2bf(tile[tx][ty + 8 * i]);
}

// ---- 16-micro-phase 256x256 GEMM core (frozen R7 schedule) ----
// MODE 0: combined projections (o=0 q, 1 k, 2 v-transposed), batched, early-exit
// MODE 2: scores = qc kc^T /32, bf16 out, exits on bm,bn >= nvpad
// MODE 3: PV, runtime K = nvpad[z], scatter epilogue via idx, rows < nv only

#define BAR __builtin_amdgcn_s_barrier()

#define RDQ(DST, K0, K1, QOFF)                              \
  {                                                         \
    DST[0][0] = ld8(K0, (QOFF));                            \
    DST[0][1] = ld8(K0, (QOFF) + 2048);                     \
    DST[1][0] = ld8(K1, (QOFF));                            \
    DST[1][1] = ld8(K1, (QOFF) + 2048);                     \
  }

#define RDB(DST, K0, K1, NH)                                \
  {                                                         \
    DST[0][0] = ld8(K0, (NH) * 4096);                       \
    DST[0][1] = ld8(K0, (NH) * 4096 + 2048);                \
    DST[1][0] = ld8(K1, (NH) * 4096);                       \
    DST[1][1] = ld8(K1, (NH) * 4096 + 2048);                \
  }

#define MQ(ACC, MB, NH, A2, B2)                                          \
  __builtin_amdgcn_s_setprio(1);                                         \
  {                                                                      \
    _Pragma("unroll") for (int ks_ = 0; ks_ < 2; ++ks_)                  \
        _Pragma("unroll") for (int m_ = 0; m_ < 2; ++m_)                 \
            _Pragma("unroll") for (int nf_ = 0; nf_ < 2; ++nf_)          \
                ACC[(MB) + m_][(NH) * 2 + nf_] =                         \
                    __builtin_amdgcn_mfma_f32_16x16x32_bf16(             \
                        A2[ks_][m_], B2[ks_][nf_],                       \
                        ACC[(MB) + m_][(NH) * 2 + nf_], 0, 0, 0);        \
  }                                                                      \
  __builtin_amdgcn_s_setprio(0);

template <int MODE>
__global__ __launch_bounds__(512, 2) void gemm8p(
    const u16* __restrict__ A, const u16* __restrict__ B,
    void* __restrict__ C, void* __restrict__ C1, void* __restrict__ C2,
    const float* __restrict__ b0, const float* __restrict__ b1,
    const float* __restrict__ b2,
    const int* __restrict__ nvpadA, const int* __restrict__ nvA,
    const int* __restrict__ idxA,
    int K, int lda, int ldb, int ldc,
    size_t Az, size_t Bz, size_t Cz) {
  __shared__ __attribute__((aligned(16))) char smem[131072];
  const int tid = threadIdx.x;
  const int lane = tid & 63;
  const int w = tid >> 6;
  const int wr = w >> 2;
  const int wc = w & 3;

  // decode: batch-per-XCD (z = bx & 7)
  const int bx = blockIdx.x;
  const int z = bx & 7;
  int r = bx >> 3;
  int bm, bn, o = 0;
  if constexpr (MODE == 0) { o = r >> 5; r &= 31; bm = r >> 2; bn = r & 3; }
  else if constexpr (MODE == 2) { bm = r >> 3; bn = r & 7; }
  else { bm = r >> 2; bn = r & 3; }

  const int nvp = nvpadA[z];
  if (bm * 256 >= nvp) return;
  if constexpr (MODE == 2) { if (bn * 256 >= nvp) return; }

  const u16* Ap = A;
  const u16* Bp = B;
  if constexpr (MODE == 0) {
    Ap += (size_t)o * (8u * 2048u * 1024u) + (size_t)z * (2048u * 1024u);
    Bp += (size_t)o * (1024u * 1024u);
  } else {
    Ap += (size_t)z * Az;
    Bp += (size_t)z * Bz;
  }
  const int Kz = (MODE == 3) ? nvp : K;
  const int half = Kz >> 7;  // iterations; 2 K-tiles (BK=64) each; Kz % 256 == 0

  // staging addressing: linear LDS dest, inverse-swizzled global source
  const int srow = w * 8 + (lane >> 3);
  const int scol = ((lane & 7) ^ (lane >> 3)) << 3;  // elems
  const u16* Ab0 = Ap + (size_t)(bm * 256 + srow) * lda + scol;
  const u16* Ab1 = Ab0 + (size_t)64 * lda;
  const u16* Ab2 = Ab0 + (size_t)128 * lda;
  const u16* Ab3 = Ab0 + (size_t)192 * lda;
  const u16* Bb0 = Bp + (size_t)(bn * 256 + srow) * ldb + scol;
  const u16* Bb1 = Bb0 + (size_t)64 * ldb;
  const u16* Bb2 = Bb0 + (size_t)128 * ldb;
  const u16* Bb3 = Bb0 + (size_t)192 * ldb;
  char* ldsW = smem + w * 1024;

  // fragment read bases
  const int fr = lane & 15;
  const int fq = lane >> 4;
  const int fx = (fr & 7) << 4;
  const char* pak0 = smem + wr * 16384 + fr * 128 + ((fq * 16) ^ fx);
  const char* pak1 = smem + wr * 16384 + fr * 128 + ((64 + fq * 16) ^ fx);
  const char* pak0b = pak0 + 65536;
  const char* pak1b = pak1 + 65536;
  const char* pbk0 = smem + 32768 + wc * 8192 + fr * 128 + ((fq * 16) ^ fx);
  const char* pbk1 = smem + 32768 + wc * 8192 + fr * 128 + ((64 + fq * 16) ^ fx);
  const char* pbk0b = pbk0 + 65536;
  const char* pbk1b = pbk1 + 65536;

  f32x4 acc0[4][4] = {};
  f32x4 acc1[4][4] = {};
  short8 aA[2][2], aB[2][2], bf0[2][2], bf1[2][2];

  // prologue
  stage16(Ab0, ldsW + 0);     stage16(Ab1, ldsW + 8192);
  stage16(Ab2, ldsW + 16384); stage16(Ab3, ldsW + 24576);
  stage16(Bb0, ldsW + 32768); stage16(Bb1, ldsW + 40960);
  stage16(Bb2, ldsW + 49152); stage16(Bb3, ldsW + 57344);
  stage16(Bb0 + 64, ldsW + 98304);  stage16(Bb1 + 64, ldsW + 106496);
  stage16(Bb2 + 64, ldsW + 114688); stage16(Bb3 + 64, ldsW + 122880);
  stage16(Ab0 + 64, ldsW + 65536);
  asm volatile("s_waitcnt vmcnt(5)" ::: "memory");
  BAR;
  RDQ(aA, pak0, pak1, 0);
  RDB(bf0, pbk0, pbk1, 0);

  int koff = 0;
  for (int i = 0; i < half; ++i) {
    const bool st = (i + 1 < half);
    const int o1 = koff + 64, o2 = koff + 128, o3 = koff + 192;

    // ---- half 0: tile t0 (buf0) ----
    RDB(bf1, pbk0, pbk1, 1);
    BAR;
    stage16(Ab1 + o1, ldsW + 65536 + 8192);
    MQ(acc0, 0, 0, aA, bf0);
    RDQ(aB, pak0, pak1, 4096);
    BAR;
    stage16(Ab2 + o1, ldsW + 65536 + 16384);
    MQ(acc0, 0, 1, aA, bf1);
    BAR;
    stage16(Ab3 + o1, ldsW + 65536 + 24576);
    MQ(acc0, 2, 0, aB, bf0);
    RDQ(aA, pak0, pak1, 8192);
    BAR;
    if (st) stage16(Bb0 + o2, ldsW + 32768);
    MQ(acc0, 2, 1, aB, bf1);
    BAR;
    if (st) stage16(Bb1 + o2, ldsW + 40960);
    MQ(acc1, 0, 0, aA, bf0);
    RDQ(aB, pak0, pak1, 12288);
    BAR;
    if (st) stage16(Bb2 + o2, ldsW + 49152);
    MQ(acc1, 0, 1, aA, bf1);
    BAR;
    if (st) stage16(Bb3 + o2, ldsW + 57344);
    MQ(acc1, 2, 0, aB, bf0);
    if (st) { asm volatile("s_waitcnt vmcnt(4)" ::: "memory"); }
    else    { asm volatile("s_waitcnt vmcnt(0)" ::: "memory"); }
    BAR;
    RDQ(aA, pak0b, pak1b, 0);
    RDB(bf0, pbk0b, pbk1b, 0);
    if (st) stage16(Ab0 + o2, ldsW + 0);
    MQ(acc1, 2, 1, aB, bf1);

    // ---- half 1: tile t1 (buf1) ----
    RDB(bf1, pbk0b, pbk1b, 1);
    BAR;
    if (st) stage16(Ab1 + o2, ldsW + 8192);
    MQ(acc0, 0, 0, aA, bf0);
    RDQ(aB, pak0b, pak1b, 4096);
    BAR;
    if (st) stage16(Ab2 + o2, ldsW + 16384);
    MQ(acc0, 0, 1, aA, bf1);
    BAR;
    if (st) stage16(Ab3 + o2, ldsW + 24576);
    MQ(acc0, 2, 0, aB, bf0);
    RDQ(aA, pak0b, pak1b, 8192);
    BAR;
    if (st) stage16(Bb0 + o3, ldsW + 98304);
    MQ(acc0, 2, 1, aB, bf1);
    BAR;
    if (st) stage16(Bb1 + o3, ldsW + 106496);
    MQ(acc1, 0, 0, aA, bf0);
    RDQ(aB, pak0b, pak1b, 12288);
    BAR;
    if (st) stage16(Bb2 + o3, ldsW + 114688);
    MQ(acc1, 0, 1, aA, bf1);
    BAR;
    if (st) stage16(Bb3 + o3, ldsW + 122880);
    MQ(acc1, 2, 0, aB, bf0);
    if (st) { asm volatile("s_waitcnt vmcnt(4)" ::: "memory"); }
    else    { asm volatile("s_waitcnt vmcnt(0)" ::: "memory"); }
    BAR;
    RDQ(aA, pak0, pak1, 0);
    RDB(bf0, pbk0, pbk1, 0);
    if (st) stage16(Ab0 + o3, ldsW + 65536);
    MQ(acc1, 2, 1, aB, bf1);

    koff += 128;
  }

  // epilogue. D frag layout: col = fr, row = fq*4 + j.
  const int colb = bn * 256 + wc * 64 + fr;
#pragma unroll
  for (int mh = 0; mh < 2; ++mh) {
    f32x4(&ac)[4][4] = mh ? acc1 : acc0;
    const int rowl = bm * 256 + wr * 128 + mh * 64 + fq * 4;  // local row
    if constexpr (MODE == 0) {
      if (o < 2) {
        const float* bp = o ? b1 : b0;
        u16* Cb = (u16*)(o ? C1 : C) + (size_t)z * (2048u * 1024u);
#pragma unroll
        for (int mf = 0; mf < 4; ++mf)
#pragma unroll
          for (int n = 0; n < 4; ++n) {
            const int c = colb + n * 16;
            const float bv = bp[c];
#pragma unroll
            for (int j = 0; j < 4; ++j)
              Cb[(size_t)(rowl + mf * 16 + j) * 1024 + c] =
                  f2bf(ac[mf][n][j] + bv);
          }
      } else {
        u16* Cb = (u16*)C2;  // vcT [8][1024][2048]
#pragma unroll
        for (int mf = 0; mf < 4; ++mf) {
          const int s_ = rowl + mf * 16;
#pragma unroll
          for (int n = 0; n < 4; ++n) {
            const int c = colb + n * 16;
            const float bv = b2[c];
            ushort4 ov;
            ov.x = f2bf(ac[mf][n][0] + bv);
            ov.y = f2bf(ac[mf][n][1] + bv);
            ov.z = f2bf(ac[mf][n][2] + bv);
            ov.w = f2bf(ac[mf][n][3] + bv);
            *(ushort4*)&Cb[((size_t)z * 1024 + c) * 2048 + s_] = ov;
          }
        }
      }
    } else if constexpr (MODE == 2) {
      u16* Cb = (u16*)C + (size_t)z * Cz;
#pragma unroll
      for (int mf = 0; mf < 4; ++mf)
#pragma unroll
        for (int n = 0; n < 4; ++n) {
          const int c = colb + n * 16;
#pragma unroll
          for (int j = 0; j < 4; ++j)
            Cb[(size_t)(rowl + mf * 16 + j) * ldc + c] =
                f2bf(ac[mf][n][j] * 0.03125f);
        }
    } else {  // MODE 3: scatter to d_out via idx, rows < nv only
      const int nv = nvA[z];
      const int* idxp = idxA + z * 2048;
      float* Ob = (float*)C;
#pragma unroll
      for (int mf = 0; mf < 4; ++mf)
#pragma unroll
        for (int j = 0; j < 4; ++j) {
          const int rowc = rowl + mf * 16 + j;
          if (rowc < nv) {
            const int gr = idxp[rowc];
            float* orow = Ob + ((size_t)z * 2048 + gr) * 1024;
#pragma unroll
            for (int n = 0; n < 4; ++n) orow[colb + n * 16] = ac[mf][n][j];
          }
        }
    }
  }
}

// ---- softmax on compacted rows: cols < nv softmaxed, [nv, nvpad) zeroed ----
__global__ __launch_bounds__(256) void softmaxc(u16* __restrict__ scores,
                                                const int* __restrict__ nvA,
                                                const int* __restrict__ nvpadA) {
  const int b = blockIdx.y, row = blockIdx.x;
  const int nv = nvA[b];
  if (row >= nv) return;
  const int nvp = nvpadA[b];
  const int t = threadIdx.x, lane = t & 63, w = t >> 6;
  u16* sc = scores + ((size_t)b * 2048 + row) * 2048;
  const int c0 = t * 8;
  float v[8];
  if (c0 < nvp) {
    const ushort4 h0 = *(const ushort4*)&sc[c0];
    const ushort4 h1 = *(const ushort4*)&sc[c0 + 4];
    v[0] = bf2f(h0.x); v[1] = bf2f(h0.y); v[2] = bf2f(h0.z); v[3] = bf2f(h0.w);
    v[4] = bf2f(h1.x); v[5] = bf2f(h1.y); v[6] = bf2f(h1.z); v[7] = bf2f(h1.w);
  } else {
#pragma unroll
    for (int i = 0; i < 8; ++i) v[i] = 0.f;
  }
  float lmax = -3.0e38f;
#pragma unroll
  for (int i = 0; i < 8; ++i)
    if (c0 + i < nv) lmax = fmaxf(lmax, v[i]);
#pragma unroll
  for (int off = 32; off >= 1; off >>= 1) lmax = fmaxf(lmax, __shfl_xor(lmax, off));
  __shared__ float red[8];
  if (lane == 0) red[w] = lmax;
  __syncthreads();
  const float bmax = fmaxf(fmaxf(red[0], red[1]), fmaxf(red[2], red[3]));
  float e[8];
  float lsum = 0.f;
#pragma unroll
  for (int i = 0; i < 8; ++i) {
    e[i] = (c0 + i < nv) ? __expf(v[i] - bmax) : 0.f;
    lsum += e[i];
  }
#pragma unroll
  for (int off = 32; off >= 1; off >>= 1) lsum += __shfl_xor(lsum, off);
  if (lane == 0) red[4 + w] = lsum;
  __syncthreads();
  const float inv = 1.0f / ((red[4] + red[5]) + (red[6] + red[7]));
  if (c0 < nvp) {
    ushort4 o0, o1;
    o0.x = f2bf(e[0] * inv); o0.y = f2bf(e[1] * inv);
    o0.z = f2bf(e[2] * inv); o0.w = f2bf(e[3] * inv);
    o1.x = f2bf(e[4] * inv); o1.y = f2bf(e[5] * inv);
    o1.z = f2bf(e[6] * inv); o1.w = f2bf(e[7] * inv);
    *(ushort4*)&sc[c0] = o0;
    *(ushort4*)&sc[c0 + 4] = o1;
  }
}

extern "C" void kernel_launch(void* const* d_in, const int* in_sizes, int n_in,
                              void* d_out, int out_size, void* d_ws, size_t ws_size,
                              hipStream_t stream) {
  const float* in_q = (const float*)d_in[0];
  const float* in_k = (const float*)d_in[1];
  const float* in_v = (const float*)d_in[2];
  const int* mask = (const int*)d_in[3];
  const float* Wq = (const float*)d_in[4];
  const float* bq = (const float*)d_in[5];
  const float* Wk = (const float*)d_in[6];
  const float* bk = (const float*)d_in[7];
  const float* Wv = (const float*)d_in[8];
  const float* bv = (const float*)d_in[9];

  char* ws = (char*)d_ws;
  const size_t SZ = (size_t)16384 * 1024 * 2;  // 32M bytes
  u16* qc = (u16*)(ws);
  u16* kc = (u16*)(ws + SZ);
  u16* vcT = (u16*)(ws + 2 * SZ);
  u16* Xc = (u16*)(ws + 3 * SZ);        // Xqc, Xkc, Xvc (32M each)
  u16* Xqc = Xc;
  u16* Xkc = Xc + (size_t)8 * 2048 * 1024;
  u16* Xvc = Xkc + (size_t)8 * 2048 * 1024;
  u16* scores = (u16*)(ws + 3 * SZ);    // overlays Xc after projections
  u16* WqT = (u16*)(ws + 6 * SZ);
  u16* WkT = WqT + 1024 * 1024;
  u16* WvT = WkT + 1024 * 1024;
  char* misc = ws + 6 * SZ + 6 * 1024 * 1024;
  int* idxA = (int*)misc;               // [8][2048] = 64KB
  int* nvA = idxA + 8 * 2048;
  int* nvpadA = nvA + 8;
  float* partial = (float*)(misc + 128 * 1024);  // [8][8][1024] = 256KB
  float* vmean = (float*)(misc + 384 * 1024);    // [8][1024] = 32KB
  float* vpart = (float*)(misc + 448 * 1024);    // [8][8][1024] = 256KB
  float* meanX = (float*)(misc + 704 * 1024);    // [8][1024] = 32KB

  // 1) mask scan -> idx, nv, nvpad
  maskscan<<<8, 256, 0, stream>>>(mask, idxA, nvA, nvpadA);

  // 2) compact-convert valid rows; vmean path (parallel)
  compactrow<<<dim3(2048, 8), 256, 0, stream>>>(in_q, idxA, nvA, Xqc);
  compactrow<<<dim3(2048, 8), 256, 0, stream>>>(in_k, idxA, nvA, Xkc);
  compactrow<<<dim3(2048, 8), 256, 0, stream>>>(in_v, idxA, nvA, Xvc);
  colpart<<<dim3(8, 4, 8), 256, 0, stream>>>(in_v, partial);
  meanx<<<dim3(8, 4), 256, 0, stream>>>(partial, meanX);
  vpartk<<<dim3(8, 4, 8), 256, 0, stream>>>(meanX, Wv, vpart);
  vmeanred<<<dim3(8, 4), 256, 0, stream>>>(vpart, bv, vmean);

  // 3) weight transposes
  dim3 wtb(32, 8);
  wtrans<<<dim3(32, 32), wtb, 0, stream>>>(Wq, WqT);
  wtrans<<<dim3(32, 32), wtb, 0, stream>>>(Wk, WkT);
  wtrans<<<dim3(32, 32), wtb, 0, stream>>>(Wv, WvT);

  // 4) all three projections, one dispatch: grid 8z * (3o * 8bm * 4bn) = 768
  gemm8p<0><<<768, 512, 0, stream>>>(
      Xqc, WqT, qc, kc, vcT, bq, bk, bv, nvpadA, nvA, idxA,
      1024, 1024, 1024, 1024, 0, 0, 0);

  // 5) scores[b] = qc kc^T / 32 : grid 8z * (8bm * 8bn) = 512
  gemm8p<2><<<512, 512, 0, stream>>>(
      qc, kc, scores, nullptr, nullptr, nullptr, nullptr, nullptr,
      nvpadA, nvA, idxA, 1024, 1024, 1024, 2048,
      (size_t)2048 * 1024, (size_t)2048 * 1024, (size_t)2048 * 2048);

  // 6) compacted softmax (in place)
  softmaxc<<<dim3(2048, 8), 256, 0, stream>>>(scores, nvA, nvpadA);

  // 7) PV with scatter: grid 8z * (8bm * 4bn) = 256; K = nvpad[z]
  gemm8p<3><<<256, 512, 0, stream>>>(
      scores, vcT, d_out, nullptr, nullptr, nullptr, nullptr, nullptr,
      nvpadA, nvA, idxA, 0, 2048, 2048, 1024,
      (size_t)2048 * 2048, (size_t)1024 * 2048, 0);

  // 8) masked q-rows: out = vmean
  bcast<<<dim3(2048, 8), 256, 0, stream>>>(mask, vmean, (float*)d_out);
}

// Round 11
// 281.609 us; speedup vs baseline: 1.3864x; 1.0487x over previous
//
#include <hip/hip_runtime.h>
#include <stdint.h>

// SelfAttentionV3 with mask-compaction. B=8, S=2048, D=1024.
// Valid rows (mask==1) are compacted per batch (nv, idx); projections, scores,
// softmax, PV run on nv_pad rows/cols only. Masked q-rows get
// out = (mean Xv)·Wv + bv exactly (uniform softmax over all 2048 rows).
// GEMM core: bf16 MFMA 256x256 tile, BK=64, 16 micro-phase read-ahead schedule
// (frozen from R7), XOR-swizzled LDS, counted vmcnt, setprio, batch->XCD map.
// R11: helper fusion — compactrow x3 -> 1, wtrans x3 -> 1, meanx folded into
// vpartk. 15 -> 11 dispatches. GEMM core untouched.

typedef unsigned short u16;
typedef __attribute__((ext_vector_type(8))) short short8;
typedef __attribute__((ext_vector_type(4))) float f32x4;

__device__ __forceinline__ u16 f2bf(float x) {
  unsigned u = __float_as_uint(x);
  return (u16)((u + 0x7FFFu + ((u >> 16) & 1u)) >> 16);  // RNE
}
__device__ __forceinline__ float bf2f(u16 h) {
  return __uint_as_float(((unsigned)h) << 16);
}

__device__ __forceinline__ void stage16(const void* g, void* l) {
  const __attribute__((address_space(1))) uint32_t* gp =
      (const __attribute__((address_space(1))) uint32_t*)(uintptr_t)g;
  __attribute__((address_space(3))) uint32_t* lp =
      (__attribute__((address_space(3))) uint32_t*)(uintptr_t)l;
  __builtin_amdgcn_global_load_lds(gp, lp, 16, 0, 0);
}

__device__ __forceinline__ short8 ld8(const char* p, int off) {
  return *(const short8*)(p + off);
}

// ---- mask prefix-scan: per batch -> idx list, nv, nvpad ----
__global__ __launch_bounds__(256) void maskscan(const int* __restrict__ mask,
                                                int* __restrict__ idxA,
                                                int* __restrict__ nvA,
                                                int* __restrict__ nvpadA) {
  const int b = blockIdx.x;
  const int t = threadIdx.x, lane = t & 63, w = t >> 6;
  const int* m = mask + b * 2048;
  int v[8], loc = 0;
#pragma unroll
  for (int i = 0; i < 8; ++i) { v[i] = m[t * 8 + i]; loc += v[i]; }
  int sc = loc;  // inclusive scan over 64 lanes
  for (int off = 1; off < 64; off <<= 1) {
    int n = __shfl_up(sc, off);
    if (lane >= off) sc += n;
  }
  __shared__ int wsum[4];
  if (lane == 63) wsum[w] = sc;
  __syncthreads();
  int woff = 0;
  for (int i = 0; i < w; ++i) woff += wsum[i];
  int pos = woff + sc - loc;  // exclusive prefix
#pragma unroll
  for (int i = 0; i < 8; ++i)
    if (v[i]) idxA[b * 2048 + (pos++)] = t * 8 + i;
  if (t == 255) {
    const int nv = woff + sc;
    nvA[b] = nv;
    nvpadA[b] = (nv + 255) & ~255;
  }
}

// ---- fused gather+convert for q,k,v (z selects input) ----
__global__ __launch_bounds__(256) void compact3(const float* __restrict__ Xq,
                                                const float* __restrict__ Xk,
                                                const float* __restrict__ Xv,
                                                const int* __restrict__ idxA,
                                                const int* __restrict__ nvA,
                                                u16* __restrict__ Oq,
                                                u16* __restrict__ Ok,
                                                u16* __restrict__ Ov) {
  const int b = blockIdx.y, j = blockIdx.x, z = blockIdx.z;
  if (j >= nvA[b]) return;
  const float* X = (z == 0) ? Xq : (z == 1) ? Xk : Xv;
  u16* out = (z == 0) ? Oq : (z == 1) ? Ok : Ov;
  const int src = idxA[b * 2048 + j];
  const float4* s = (const float4*)(X + ((size_t)b * 2048 + src) * 1024);
  ushort4* d = (ushort4*)(out + ((size_t)b * 2048 + j) * 1024);
  const float4 f = s[threadIdx.x];
  ushort4 o;
  o.x = f2bf(f.x); o.y = f2bf(f.y); o.z = f2bf(f.z); o.w = f2bf(f.w);
  d[threadIdx.x] = o;
}

// ---- column partial sums of Xv (all 2048 rows) ----
__global__ __launch_bounds__(256) void colpart(const float* __restrict__ X,
                                               float* __restrict__ partial) {
  const int b = blockIdx.x, dq = blockIdx.y, sck = blockIdx.z;
  const int d = dq * 256 + threadIdx.x;
  const float* p = X + ((size_t)b * 2048 + sck * 256) * 1024 + d;
  float s0 = 0, s1 = 0, s2 = 0, s3 = 0;
  for (int r = 0; r < 256; r += 4) {
    s0 += p[(size_t)(r + 0) * 1024];
    s1 += p[(size_t)(r + 1) * 1024];
    s2 += p[(size_t)(r + 2) * 1024];
    s3 += p[(size_t)(r + 3) * 1024];
  }
  partial[((size_t)b * 8 + sck) * 1024 + d] = (s0 + s1) + (s2 + s3);
}

// ---- vpart[b][dk][c] = sum_{d in chunk} meanX[b][d]*Wv[d][c]; meanX folded ----
__global__ __launch_bounds__(256) void vpartk(const float* __restrict__ partial,
                                              const float* __restrict__ Wv,
                                              float* __restrict__ vpart) {
  const int b = blockIdx.x, cq = blockIdx.y, dk = blockIdx.z;
  const int t = threadIdx.x;
  __shared__ float mx[128];
  if (t < 128) {
    const int d = dk * 128 + t;
    float m = 0;
#pragma unroll
    for (int i = 0; i < 8; ++i) m += partial[((size_t)b * 8 + i) * 1024 + d];
    mx[t] = m * (1.0f / 2048.0f);
  }
  __syncthreads();
  const int c = cq * 256 + t;
  const float* wp = Wv + (size_t)(dk * 128) * 1024 + c;
  float acc = 0;
#pragma unroll 4
  for (int i = 0; i < 128; ++i) acc += mx[i] * wp[(size_t)i * 1024];
  vpart[((size_t)b * 8 + dk) * 1024 + c] = acc;
}

// ---- vmean[b][c] = bv[c] + sum_dk vpart[b][dk][c] ----
__global__ __launch_bounds__(256) void vmeanred(const float* __restrict__ vpart,
                                                const float* __restrict__ bv,
                                                float* __restrict__ vmean) {
  const int b = blockIdx.x;
  const int c = blockIdx.y * 256 + threadIdx.x;
  float acc = bv[c];
#pragma unroll
  for (int i = 0; i < 8; ++i) acc += vpart[((size_t)b * 8 + i) * 1024 + c];
  vmean[b * 1024 + c] = acc;
}

// ---- out rows for masked q: broadcast vmean ----
__global__ __launch_bounds__(256) void bcast(const int* __restrict__ mask,
                                             const float* __restrict__ vmean,
                                             float* __restrict__ out) {
  const int b = blockIdx.y, row = blockIdx.x;
  if (mask[b * 2048 + row] != 0) return;
  const float4 vv = ((const float4*)(vmean + b * 1024))[threadIdx.x];
  ((float4*)(out + ((size_t)b * 2048 + row) * 1024))[threadIdx.x] = vv;
}

// ---- fused weight transpose (z selects Wq/Wk/Wv) ----
__global__ __launch_bounds__(256) void wtrans3(const float* __restrict__ Wq,
                                               const float* __restrict__ Wk,
                                               const float* __restrict__ Wv,
                                               u16* __restrict__ WT) {
  __shared__ float tile[32][33];
  const int z = blockIdx.z;
  const float* W = (z == 0) ? Wq : (z == 1) ? Wk : Wv;
  u16* out = WT + (size_t)z * 1024 * 1024;
  const int tx = threadIdx.x, ty = threadIdx.y;  // 32 x 8
  const int d0 = blockIdx.y * 32, n0 = blockIdx.x * 32;
#pragma unroll
  for (int i = 0; i < 4; ++i)
    tile[ty + 8 * i][tx] = W[(size_t)(d0 + ty + 8 * i) * 1024 + n0 + tx];
  __syncthreads();
#pragma unroll
  for (int i = 0; i < 4; ++i)
    out[(size_t)(n0 + ty + 8 * i) * 1024 + d0 + tx] = f2bf(tile[tx][ty + 8 * i]);
}

// ---- 16-micro-phase 256x256 GEMM core (frozen R7 schedule) ----
// MODE 0: combined projections (o=0 q, 1 k, 2 v-transposed), batched, early-exit
// MODE 2: scores = qc kc^T /32, bf16 out, exits on bm,bn >= nvpad
// MODE 3: PV, runtime K = nvpad[z], scatter epilogue via idx, rows < nv only

#define BAR __builtin_amdgcn_s_barrier()

#define RDQ(DST, K0, K1, QOFF)                              \
  {                                                         \
    DST[0][0] = ld8(K0, (QOFF));                            \
    DST[0][1] = ld8(K0, (QOFF) + 2048);                     \
    DST[1][0] = ld8(K1, (QOFF));                            \
    DST[1][1] = ld8(K1, (QOFF) + 2048);                     \
  }

#define RDB(DST, K0, K1, NH)                                \
  {                                                         \
    DST[0][0] = ld8(K0, (NH) * 4096);                       \
    DST[0][1] = ld8(K0, (NH) * 4096 + 2048);                \
    DST[1][0] = ld8(K1, (NH) * 4096);                       \
    DST[1][1] = ld8(K1, (NH) * 4096 + 2048);                \
  }

#define MQ(ACC, MB, NH, A2, B2)                                          \
  __builtin_amdgcn_s_setprio(1);                                         \
  {                                                                      \
    _Pragma("unroll") for (int ks_ = 0; ks_ < 2; ++ks_)                  \
        _Pragma("unroll") for (int m_ = 0; m_ < 2; ++m_)                 \
            _Pragma("unroll") for (int nf_ = 0; nf_ < 2; ++nf_)          \
                ACC[(MB) + m_][(NH) * 2 + nf_] =                         \
                    __builtin_amdgcn_mfma_f32_16x16x32_bf16(             \
                        A2[ks_][m_], B2[ks_][nf_],                       \
                        ACC[(MB) + m_][(NH) * 2 + nf_], 0, 0, 0);        \
  }                                                                      \
  __builtin_amdgcn_s_setprio(0);

template <int MODE>
__global__ __launch_bounds__(512, 2) void gemm8p(
    const u16* __restrict__ A, const u16* __restrict__ B,
    void* __restrict__ C, void* __restrict__ C1, void* __restrict__ C2,
    const float* __restrict__ b0, const float* __restrict__ b1,
    const float* __restrict__ b2,
    const int* __restrict__ nvpadA, const int* __restrict__ nvA,
    const int* __restrict__ idxA,
    int K, int lda, int ldb, int ldc,
    size_t Az, size_t Bz, size_t Cz) {
  __shared__ __attribute__((aligned(16))) char smem[131072];
  const int tid = threadIdx.x;
  const int lane = tid & 63;
  const int w = tid >> 6;
  const int wr = w >> 2;
  const int wc = w & 3;

  // decode: batch-per-XCD (z = bx & 7)
  const int bx = blockIdx.x;
  const int z = bx & 7;
  int r = bx >> 3;
  int bm, bn, o = 0;
  if constexpr (MODE == 0) { o = r >> 5; r &= 31; bm = r >> 2; bn = r & 3; }
  else if constexpr (MODE == 2) { bm = r >> 3; bn = r & 7; }
  else { bm = r >> 2; bn = r & 3; }

  const int nvp = nvpadA[z];
  if (bm * 256 >= nvp) return;
  if constexpr (MODE == 2) { if (bn * 256 >= nvp) return; }

  const u16* Ap = A;
  const u16* Bp = B;
  if constexpr (MODE == 0) {
    Ap += (size_t)o * (8u * 2048u * 1024u) + (size_t)z * (2048u * 1024u);
    Bp += (size_t)o * (1024u * 1024u);
  } else {
    Ap += (size_t)z * Az;
    Bp += (size_t)z * Bz;
  }
  const int Kz = (MODE == 3) ? nvp : K;
  const int half = Kz >> 7;  // iterations; 2 K-tiles (BK=64) each; Kz % 256 == 0

  // staging addressing: linear LDS dest, inverse-swizzled global source
  const int srow = w * 8 + (lane >> 3);
  const int scol = ((lane & 7) ^ (lane >> 3)) << 3;  // elems
  const u16* Ab0 = Ap + (size_t)(bm * 256 + srow) * lda + scol;
  const u16* Ab1 = Ab0 + (size_t)64 * lda;
  const u16* Ab2 = Ab0 + (size_t)128 * lda;
  const u16* Ab3 = Ab0 + (size_t)192 * lda;
  const u16* Bb0 = Bp + (size_t)(bn * 256 + srow) * ldb + scol;
  const u16* Bb1 = Bb0 + (size_t)64 * ldb;
  const u16* Bb2 = Bb0 + (size_t)128 * ldb;
  const u16* Bb3 = Bb0 + (size_t)192 * ldb;
  char* ldsW = smem + w * 1024;

  // fragment read bases
  const int fr = lane & 15;
  const int fq = lane >> 4;
  const int fx = (fr & 7) << 4;
  const char* pak0 = smem + wr * 16384 + fr * 128 + ((fq * 16) ^ fx);
  const char* pak1 = smem + wr * 16384 + fr * 128 + ((64 + fq * 16) ^ fx);
  const char* pak0b = pak0 + 65536;
  const char* pak1b = pak1 + 65536;
  const char* pbk0 = smem + 32768 + wc * 8192 + fr * 128 + ((fq * 16) ^ fx);
  const char* pbk1 = smem + 32768 + wc * 8192 + fr * 128 + ((64 + fq * 16) ^ fx);
  const char* pbk0b = pbk0 + 65536;
  const char* pbk1b = pbk1 + 65536;

  f32x4 acc0[4][4] = {};
  f32x4 acc1[4][4] = {};
  short8 aA[2][2], aB[2][2], bf0[2][2], bf1[2][2];

  // prologue
  stage16(Ab0, ldsW + 0);     stage16(Ab1, ldsW + 8192);
  stage16(Ab2, ldsW + 16384); stage16(Ab3, ldsW + 24576);
  stage16(Bb0, ldsW + 32768); stage16(Bb1, ldsW + 40960);
  stage16(Bb2, ldsW + 49152); stage16(Bb3, ldsW + 57344);
  stage16(Bb0 + 64, ldsW + 98304);  stage16(Bb1 + 64, ldsW + 106496);
  stage16(Bb2 + 64, ldsW + 114688); stage16(Bb3 + 64, ldsW + 122880);
  stage16(Ab0 + 64, ldsW + 65536);
  asm volatile("s_waitcnt vmcnt(5)" ::: "memory");
  BAR;
  RDQ(aA, pak0, pak1, 0);
  RDB(bf0, pbk0, pbk1, 0);

  int koff = 0;
  for (int i = 0; i < half; ++i) {
    const bool st = (i + 1 < half);
    const int o1 = koff + 64, o2 = koff + 128, o3 = koff + 192;

    // ---- half 0: tile t0 (buf0) ----
    RDB(bf1, pbk0, pbk1, 1);
    BAR;
    stage16(Ab1 + o1, ldsW + 65536 + 8192);
    MQ(acc0, 0, 0, aA, bf0);
    RDQ(aB, pak0, pak1, 4096);
    BAR;
    stage16(Ab2 + o1, ldsW + 65536 + 16384);
    MQ(acc0, 0, 1, aA, bf1);
    BAR;
    stage16(Ab3 + o1, ldsW + 65536 + 24576);
    MQ(acc0, 2, 0, aB, bf0);
    RDQ(aA, pak0, pak1, 8192);
    BAR;
    if (st) stage16(Bb0 + o2, ldsW + 32768);
    MQ(acc0, 2, 1, aB, bf1);
    BAR;
    if (st) stage16(Bb1 + o2, ldsW + 40960);
    MQ(acc1, 0, 0, aA, bf0);
    RDQ(aB, pak0, pak1, 12288);
    BAR;
    if (st) stage16(Bb2 + o2, ldsW + 49152);
    MQ(acc1, 0, 1, aA, bf1);
    BAR;
    if (st) stage16(Bb3 + o2, ldsW + 57344);
    MQ(acc1, 2, 0, aB, bf0);
    if (st) { asm volatile("s_waitcnt vmcnt(4)" ::: "memory"); }
    else    { asm volatile("s_waitcnt vmcnt(0)" ::: "memory"); }
    BAR;
    RDQ(aA, pak0b, pak1b, 0);
    RDB(bf0, pbk0b, pbk1b, 0);
    if (st) stage16(Ab0 + o2, ldsW + 0);
    MQ(acc1, 2, 1, aB, bf1);

    // ---- half 1: tile t1 (buf1) ----
    RDB(bf1, pbk0b, pbk1b, 1);
    BAR;
    if (st) stage16(Ab1 + o2, ldsW + 8192);
    MQ(acc0, 0, 0, aA, bf0);
    RDQ(aB, pak0b, pak1b, 4096);
    BAR;
    if (st) stage16(Ab2 + o2, ldsW + 16384);
    MQ(acc0, 0, 1, aA, bf1);
    BAR;
    if (st) stage16(Ab3 + o2, ldsW + 24576);
    MQ(acc0, 2, 0, aB, bf0);
    RDQ(aA, pak0b, pak1b, 8192);
    BAR;
    if (st) stage16(Bb0 + o3, ldsW + 98304);
    MQ(acc0, 2, 1, aB, bf1);
    BAR;
    if (st) stage16(Bb1 + o3, ldsW + 106496);
    MQ(acc1, 0, 0, aA, bf0);
    RDQ(aB, pak0b, pak1b, 12288);
    BAR;
    if (st) stage16(Bb2 + o3, ldsW + 114688);
    MQ(acc1, 0, 1, aA, bf1);
    BAR;
    if (st) stage16(Bb3 + o3, ldsW + 122880);
    MQ(acc1, 2, 0, aB, bf0);
    if (st) { asm volatile("s_waitcnt vmcnt(4)" ::: "memory"); }
    else    { asm volatile("s_waitcnt vmcnt(0)" ::: "memory"); }
    BAR;
    RDQ(aA, pak0, pak1, 0);
    RDB(bf0, pbk0, pbk1, 0);
    if (st) stage16(Ab0 + o3, ldsW + 65536);
    MQ(acc1, 2, 1, aB, bf1);

    koff += 128;
  }

  // epilogue. D frag layout: col = fr, row = fq*4 + j.
  const int colb = bn * 256 + wc * 64 + fr;
#pragma unroll
  for (int mh = 0; mh < 2; ++mh) {
    f32x4(&ac)[4][4] = mh ? acc1 : acc0;
    const int rowl = bm * 256 + wr * 128 + mh * 64 + fq * 4;  // local row
    if constexpr (MODE == 0) {
      if (o < 2) {
        const float* bp = o ? b1 : b0;
        u16* Cb = (u16*)(o ? C1 : C) + (size_t)z * (2048u * 1024u);
#pragma unroll
        for (int mf = 0; mf < 4; ++mf)
#pragma unroll
          for (int n = 0; n < 4; ++n) {
            const int c = colb + n * 16;
            const float bv = bp[c];
#pragma unroll
            for (int j = 0; j < 4; ++j)
              Cb[(size_t)(rowl + mf * 16 + j) * 1024 + c] =
                  f2bf(ac[mf][n][j] + bv);
          }
      } else {
        u16* Cb = (u16*)C2;  // vcT [8][1024][2048]
#pragma unroll
        for (int mf = 0; mf < 4; ++mf) {
          const int s_ = rowl + mf * 16;
#pragma unroll
          for (int n = 0; n < 4; ++n) {
            const int c = colb + n * 16;
            const float bv = b2[c];
            ushort4 ov;
            ov.x = f2bf(ac[mf][n][0] + bv);
            ov.y = f2bf(ac[mf][n][1] + bv);
            ov.z = f2bf(ac[mf][n][2] + bv);
            ov.w = f2bf(ac[mf][n][3] + bv);
            *(ushort4*)&Cb[((size_t)z * 1024 + c) * 2048 + s_] = ov;
          }
        }
      }
    } else if constexpr (MODE == 2) {
      u16* Cb = (u16*)C + (size_t)z * Cz;
#pragma unroll
      for (int mf = 0; mf < 4; ++mf)
#pragma unroll
        for (int n = 0; n < 4; ++n) {
          const int c = colb + n * 16;
#pragma unroll
          for (int j = 0; j < 4; ++j)
            Cb[(size_t)(rowl + mf * 16 + j) * ldc + c] =
                f2bf(ac[mf][n][j] * 0.03125f);
        }
    } else {  // MODE 3: scatter to d_out via idx, rows < nv only
      const int nv = nvA[z];
      const int* idxp = idxA + z * 2048;
      float* Ob = (float*)C;
#pragma unroll
      for (int mf = 0; mf < 4; ++mf)
#pragma unroll
        for (int j = 0; j < 4; ++j) {
          const int rowc = rowl + mf * 16 + j;
          if (rowc < nv) {
            const int gr = idxp[rowc];
            float* orow = Ob + ((size_t)z * 2048 + gr) * 1024;
#pragma unroll
            for (int n = 0; n < 4; ++n) orow[colb + n * 16] = ac[mf][n][j];
          }
        }
    }
  }
}

// ---- softmax on compacted rows: cols < nv softmaxed, [nv, nvpad) zeroed ----
__global__ __launch_bounds__(256) void softmaxc(u16* __restrict__ scores,
                                                const int* __restrict__ nvA,
                                                const int* __restrict__ nvpadA) {
  const int b = blockIdx.y, row = blockIdx.x;
  const int nv = nvA[b];
  if (row >= nv) return;
  const int nvp = nvpadA[b];
  const int t = threadIdx.x, lane = t & 63, w = t >> 6;
  u16* sc = scores + ((size_t)b * 2048 + row) * 2048;
  const int c0 = t * 8;
  float v[8];
  if (c0 < nvp) {
    const ushort4 h0 = *(const ushort4*)&sc[c0];
    const ushort4 h1 = *(const ushort4*)&sc[c0 + 4];
    v[0] = bf2f(h0.x); v[1] = bf2f(h0.y); v[2] = bf2f(h0.z); v[3] = bf2f(h0.w);
    v[4] = bf2f(h1.x); v[5] = bf2f(h1.y); v[6] = bf2f(h1.z); v[7] = bf2f(h1.w);
  } else {
#pragma unroll
    for (int i = 0; i < 8; ++i) v[i] = 0.f;
  }
  float lmax = -3.0e38f;
#pragma unroll
  for (int i = 0; i < 8; ++i)
    if (c0 + i < nv) lmax = fmaxf(lmax, v[i]);
#pragma unroll
  for (int off = 32; off >= 1; off >>= 1) lmax = fmaxf(lmax, __shfl_xor(lmax, off));
  __shared__ float red[8];
  if (lane == 0) red[w] = lmax;
  __syncthreads();
  const float bmax = fmaxf(fmaxf(red[0], red[1]), fmaxf(red[2], red[3]));
  float e[8];
  float lsum = 0.f;
#pragma unroll
  for (int i = 0; i < 8; ++i) {
    e[i] = (c0 + i < nv) ? __expf(v[i] - bmax) : 0.f;
    lsum += e[i];
  }
#pragma unroll
  for (int off = 32; off >= 1; off >>= 1) lsum += __shfl_xor(lsum, off);
  if (lane == 0) red[4 + w] = lsum;
  __syncthreads();
  const float inv = 1.0f / ((red[4] + red[5]) + (red[6] + red[7]));
  if (c0 < nvp) {
    ushort4 o0, o1;
    o0.x = f2bf(e[0] * inv); o0.y = f2bf(e[1] * inv);
    o0.z = f2bf(e[2] * inv); o0.w = f2bf(e[3] * inv);
    o1.x = f2bf(e[4] * inv); o1.y = f2bf(e[5] * inv);
    o1.z = f2bf(e[6] * inv); o1.w = f2bf(e[7] * inv);
    *(ushort4*)&sc[c0] = o0;
    *(ushort4*)&sc[c0 + 4] = o1;
  }
}

extern "C" void kernel_launch(void* const* d_in, const int* in_sizes, int n_in,
                              void* d_out, int out_size, void* d_ws, size_t ws_size,
                              hipStream_t stream) {
  const float* in_q = (const float*)d_in[0];
  const float* in_k = (const float*)d_in[1];
  const float* in_v = (const float*)d_in[2];
  const int* mask = (const int*)d_in[3];
  const float* Wq = (const float*)d_in[4];
  const float* bq = (const float*)d_in[5];
  const float* Wk = (const float*)d_in[6];
  const float* bk = (const float*)d_in[7];
  const float* Wv = (const float*)d_in[8];
  const float* bv = (const float*)d_in[9];

  char* ws = (char*)d_ws;
  const size_t SZ = (size_t)16384 * 1024 * 2;  // 32M bytes
  u16* qc = (u16*)(ws);
  u16* kc = (u16*)(ws + SZ);
  u16* vcT = (u16*)(ws + 2 * SZ);
  u16* Xc = (u16*)(ws + 3 * SZ);        // Xqc, Xkc, Xvc (32M each)
  u16* Xqc = Xc;
  u16* Xkc = Xc + (size_t)8 * 2048 * 1024;
  u16* Xvc = Xkc + (size_t)8 * 2048 * 1024;
  u16* scores = (u16*)(ws + 3 * SZ);    // overlays Xc after projections
  u16* WT = (u16*)(ws + 6 * SZ);        // WqT, WkT, WvT contiguous
  char* misc = ws + 6 * SZ + 6 * 1024 * 1024;
  int* idxA = (int*)misc;               // [8][2048] = 64KB
  int* nvA = idxA + 8 * 2048;
  int* nvpadA = nvA + 8;
  float* partial = (float*)(misc + 128 * 1024);  // [8][8][1024] = 256KB
  float* vmean = (float*)(misc + 384 * 1024);    // [8][1024] = 32KB
  float* vpart = (float*)(misc + 448 * 1024);    // [8][8][1024] = 256KB

  // 1) mask scan -> idx, nv, nvpad
  maskscan<<<8, 256, 0, stream>>>(mask, idxA, nvA, nvpadA);

  // 2) fused gather+convert (q,k,v in one dispatch); vmean path
  compact3<<<dim3(2048, 8, 3), 256, 0, stream>>>(in_q, in_k, in_v, idxA, nvA,
                                                 Xqc, Xkc, Xvc);
  colpart<<<dim3(8, 4, 8), 256, 0, stream>>>(in_v, partial);
  vpartk<<<dim3(8, 4, 8), 256, 0, stream>>>(partial, Wv, vpart);
  vmeanred<<<dim3(8, 4), 256, 0, stream>>>(vpart, bv, vmean);

  // 3) fused weight transposes (one dispatch)
  wtrans3<<<dim3(32, 32, 3), dim3(32, 8), 0, stream>>>(Wq, Wk, Wv, WT);

  // 4) all three projections, one dispatch: grid 8z * (3o * 8bm * 4bn) = 768
  gemm8p<0><<<768, 512, 0, stream>>>(
      Xqc, WT, qc, kc, vcT, bq, bk, bv, nvpadA, nvA, idxA,
      1024, 1024, 1024, 1024, 0, 0, 0);

  // 5) scores[b] = qc kc^T / 32 : grid 8z * (8bm * 8bn) = 512
  gemm8p<2><<<512, 512, 0, stream>>>(
      qc, kc, scores, nullptr, nullptr, nullptr, nullptr, nullptr,
      nvpadA, nvA, idxA, 1024, 1024, 1024, 2048,
      (size_t)2048 * 1024, (size_t)2048 * 1024, (size_t)2048 * 2048);

  // 6) compacted softmax (in place)
  softmaxc<<<dim3(2048, 8), 256, 0, stream>>>(scores, nvA, nvpadA);

  // 7) PV with scatter: grid 8z * (8bm * 4bn) = 256; K = nvpad[z]
  gemm8p<3><<<256, 512, 0, stream>>>(
      scores, vcT, d_out, nullptr, nullptr, nullptr, nullptr, nullptr,
      nvpadA, nvA, idxA, 0, 2048, 2048, 1024,
      (size_t)2048 * 2048, (size_t)1024 * 2048, 0);

  // 8) masked q-rows: out = vmean
  bcast<<<dim3(2048, 8), 256, 0, stream>>>(mask, vmean, (float*)d_out);
}